// Round 7
// baseline (810.841 us; speedup 1.0000x reference)
//
#include <hip/hip_runtime.h>

// SpatialAttention B=4 HW=4096 C=256 NH=4 d=64 — f16 MFMA flash attention.
// R7: QTILE=256 (512-thr blocks) halves L2/L3 fabric staging traffic (the
// R5/R6 ~4.4TB/s plateau); 4-way key split + launch_bounds(512,8) -> 32
// waves/CU; Vthat stored in PV-fragment order with baked XOR swizzle ->
// 8 conflict-free b128 V reads; per-lane deferred l (sum shfls out of loop);
// wave-uniform skip-rescale.

#define HW 4096
#define CCH 256
#define DH 64
#define NH 4
#define QTILE 256
#define KTILE 64
#define NSPLIT 4
#define NKT_SPLIT (HW / NSPLIT / KTILE)   // 16
#define LOG2E 1.44269504088896340736f

typedef __attribute__((ext_vector_type(8))) _Float16 half8;
typedef __attribute__((ext_vector_type(4))) _Float16 half4;
typedef __attribute__((ext_vector_type(2))) __fp16 pk16x2;   // cvt_pkrtz native type
typedef __attribute__((ext_vector_type(4))) float floatx4;

typedef __attribute__((address_space(1))) const unsigned int gbl_u32;
typedef __attribute__((address_space(3))) unsigned int lds_u32;

__device__ __forceinline__ void gload_lds16(const void* g, void* l) {
    __builtin_amdgcn_global_load_lds((gbl_u32*)g, (lds_u32*)l, 16, 0, 0);
}
__device__ __forceinline__ floatx4 mfma_k32(half8 a, half8 b, floatx4 c) {
    return __builtin_amdgcn_mfma_f32_16x16x32_f16(a, b, c, 0, 0, 0);
}
__device__ __forceinline__ floatx4 mfma_k16(half4 a, half4 b, floatx4 c) {
    return __builtin_amdgcn_mfma_f32_16x16x16f16(a, b, c, 0, 0, 0);
}

// ---------- fused prepass ----------
// blocks [0,4096): Qhat/Khat elementwise (scale*log2e folded into Q)
// blocks [4096,5120): Vthat transpose into PV-fragment order + XOR swizzle
__global__ __launch_bounds__(256) void prepass_all(
    const float* __restrict__ q_in, const float* __restrict__ k_in,
    const float* __restrict__ v_in,
    const float* __restrict__ wq, const float* __restrict__ bq,
    const float* __restrict__ wk, const float* __restrict__ bk,
    const float* __restrict__ wv, const float* __restrict__ bv,
    _Float16* __restrict__ Qhat, _Float16* __restrict__ Khat,
    _Float16* __restrict__ Vthat)
{
    if (blockIdx.x < 4096) {
        int idx = (blockIdx.x * 256 + threadIdx.x) * 4;
        int b = idx >> 20;
        int rem = idx & ((1 << 20) - 1);
        int row = rem >> 8;
        int c = rem & 255;
        int h = c >> 6;
        int ch = c & 63;
        floatx4 q4 = *(const floatx4*)(q_in + idx);
        floatx4 k4 = *(const floatx4*)(k_in + idx);
        floatx4 wq4 = *(const floatx4*)(wq + c);
        floatx4 bq4 = *(const floatx4*)(bq + c);
        floatx4 wk4 = *(const floatx4*)(wk + c);
        floatx4 bk4 = *(const floatx4*)(bk + c);
        const float qsc = 0.125f * LOG2E;
        half4 qh, kh;
        qh[0] = (_Float16)((q4.x * wq4.x + bq4.x) * qsc);
        qh[1] = (_Float16)((q4.y * wq4.y + bq4.y) * qsc);
        qh[2] = (_Float16)((q4.z * wq4.z + bq4.z) * qsc);
        qh[3] = (_Float16)((q4.w * wq4.w + bq4.w) * qsc);
        kh[0] = (_Float16)(k4.x * wk4.x + bk4.x);
        kh[1] = (_Float16)(k4.y * wk4.y + bk4.y);
        kh[2] = (_Float16)(k4.z * wk4.z + bk4.z);
        kh[3] = (_Float16)(k4.w * wk4.w + bk4.w);
        size_t o = ((size_t)(b * NH + h) * HW + row) * DH + ch;
        *(half4*)(Qhat + o) = qh;
        *(half4*)(Khat + o) = kh;
    } else {
        __shared__ _Float16 Lt[64 * 68];
        int bx = blockIdx.x - 4096;
        int t = threadIdx.x;
        int key0 = (bx & 63) * 64;
        int bh = bx >> 6;
        int b = bh >> 2, h = bh & 3;
        int c4 = (t & 15) * 4;
        floatx4 wv4 = *(const floatx4*)(wv + h * DH + c4);
        floatx4 bv4 = *(const floatx4*)(bv + h * DH + c4);
        #pragma unroll
        for (int p = 0; p < 4; ++p) {
            int key = p * 16 + (t >> 4);
            const float* vp = v_in + ((size_t)b * HW + key0 + key) * CCH + h * DH + c4;
            floatx4 v4 = *(const floatx4*)vp;
            half4 vh;
            vh[0] = (_Float16)(v4.x * wv4.x + bv4.x);
            vh[1] = (_Float16)(v4.y * wv4.y + bv4.y);
            vh[2] = (_Float16)(v4.z * wv4.z + bv4.z);
            vh[3] = (_Float16)(v4.w * wv4.w + bv4.w);
            *(half4*)(&Lt[key * 68 + c4]) = vh;
        }
        __syncthreads();
        // Store 64-key tile in PV-fragment order + row XOR swizzle:
        // stored position p' = ((g ^ (d&7))*8 + j), content key(g,j) where
        // key(g,j) = ((2g + (j>>2)) & 3)*16 + (g>>1)*4 + (j&3)
        #pragma unroll
        for (int p = 0; p < 2; ++p) {
            int d = p * 32 + (t >> 3);      // channel / d-row
            int gpos = t & 7;               // stored group position
            int g = gpos ^ (d & 7);         // data group (swizzle baked)
            half8 v8;
            #pragma unroll
            for (int j = 0; j < 8; ++j) {
                int key = (((g * 2 + (j >> 2)) & 3) << 4) + ((g >> 1) << 2) + (j & 3);
                v8[j] = Lt[key * 68 + d];
            }
            *(half8*)(Vthat + ((size_t)bh * DH + d) * HW + key0 + gpos * 8) = v8;
        }
    }
}

// ---------- attention (transposed, register-P, 4-way key-split) ----------
__launch_bounds__(512, 8)
__global__ void attn_kernel(
    const _Float16* __restrict__ Qhat, const _Float16* __restrict__ Khat,
    const _Float16* __restrict__ Vthat,
    _Float16* __restrict__ Pacc, float* __restrict__ Pml)
{
    // dbuf: Ksm0 | Ksm1 | Vsm0 | Vsm1 (8KB each) = 32KB -> 4 blocks/CU
    __shared__ alignas(16) char pool[32768];
    _Float16* Ksm0 = (_Float16*)(pool);
    _Float16* Ksm1 = (_Float16*)(pool + 8192);
    _Float16* Vsm0 = (_Float16*)(pool + 16384);
    _Float16* Vsm1 = (_Float16*)(pool + 24576);

    const int tid = threadIdx.x;
    const int wave = tid >> 6;     // 0..7
    const int lane = tid & 63;
    const int l15 = lane & 15;
    const int quad = lane >> 4;
    const int ksw = l15 & 7;

    const int qtile = blockIdx.x;
    const int bh = blockIdx.y;
    const int split = blockIdx.z;
    const int keybase = split * (HW / NSPLIT);

    // Q B-frags: B[k=ch][n=q], lane holds ch = quad*8+j (+32), q = l15 (+16g)
    const int q0 = qtile * QTILE + wave * 32;
    half8 qfrag[2][2];
    #pragma unroll
    for (int g = 0; g < 2; ++g) {
        const _Float16* qp = Qhat + ((size_t)bh * HW + q0 + g * 16 + l15) * DH + quad * 8;
        qfrag[g][0] = *(const half8*)(qp);
        qfrag[g][1] = *(const half8*)(qp + 32);
    }

    // staging lane addresses; 8 waves cover 64 rows (1 K + 1 V gload per wave)
    const int srow = wave * 8 + (lane >> 3);
    const int sw = (lane & 7) ^ (lane >> 3);   // K row-XOR swizzle (in global addr)
    const _Float16* kgp = Khat + ((size_t)bh * HW + keybase + srow) * DH + sw * 8;
    const _Float16* vgp = Vthat + ((size_t)bh * DH + srow) * HW + keybase + (lane & 7) * 8;

    floatx4 acc[2][4];
    float m_i[2], l_i[2];
    #pragma unroll
    for (int g = 0; g < 2; ++g) {
        m_i[g] = -1e30f; l_i[g] = 0.0f;
        #pragma unroll
        for (int nt = 0; nt < 4; ++nt) { floatx4 z = {0.f,0.f,0.f,0.f}; acc[g][nt] = z; }
    }

    #define STAGE(kt, KB, VB) do {                                             \
        gload_lds16(kgp + (size_t)(kt) * (KTILE * DH), (KB) + wave * 512);     \
        gload_lds16(vgp + (size_t)(kt) * KTILE, (VB) + wave * 512);            \
    } while (0)

    #define COMPUTE(KB, VB) do {                                               \
        floatx4 S[2][4];                                                       \
        _Pragma("unroll")                                                      \
        for (int kt = 0; kt < 4; ++kt) {                                       \
            const _Float16* kr = (KB) + (l15 + 16 * kt) * 64;                  \
            half8 kf0 = *(const half8*)(kr + ((quad ^ ksw) * 8));              \
            half8 kf1 = *(const half8*)(kr + (((4 + quad) ^ ksw) * 8));        \
            _Pragma("unroll")                                                  \
            for (int g = 0; g < 2; ++g) {                                      \
                floatx4 s = {0.f, 0.f, 0.f, 0.f};                              \
                s = mfma_k32(kf0, qfrag[g][0], s);                             \
                s = mfma_k32(kf1, qfrag[g][1], s);                             \
                S[g][kt] = s;                                                  \
            }                                                                  \
        }                                                                      \
        half4 pfrag[2][4];                                                     \
        _Pragma("unroll")                                                      \
        for (int g = 0; g < 2; ++g) {                                          \
            float mx = fmaxf(fmaxf(fmaxf(S[g][0][0], S[g][0][1]),              \
                                   fmaxf(S[g][0][2], S[g][0][3])),             \
                             fmaxf(fmaxf(S[g][1][0], S[g][1][1]),              \
                                   fmaxf(S[g][1][2], S[g][1][3])));            \
            float mx2 = fmaxf(fmaxf(fmaxf(S[g][2][0], S[g][2][1]),             \
                                    fmaxf(S[g][2][2], S[g][2][3])),            \
                              fmaxf(fmaxf(S[g][3][0], S[g][3][1]),             \
                                    fmaxf(S[g][3][2], S[g][3][3])));           \
            mx = fmaxf(mx, mx2);                                               \
            mx = fmaxf(mx, __shfl_xor(mx, 16));                                \
            mx = fmaxf(mx, __shfl_xor(mx, 32));                                \
            if (__any(mx > m_i[g])) {                                          \
                float nm = fmaxf(m_i[g], mx);                                  \
                float alpha = __builtin_amdgcn_exp2f(m_i[g] - nm);             \
                l_i[g] *= alpha;                                               \
                _Pragma("unroll")                                              \
                for (int nt = 0; nt < 4; ++nt) acc[g][nt] *= alpha;            \
                m_i[g] = nm;                                                   \
            }                                                                  \
            float nm2 = m_i[g];                                                \
            float rs = 0.0f;                                                   \
            _Pragma("unroll")                                                  \
            for (int kt = 0; kt < 4; ++kt) {                                   \
                float p0 = __builtin_amdgcn_exp2f(S[g][kt][0] - nm2);          \
                float p1 = __builtin_amdgcn_exp2f(S[g][kt][1] - nm2);          \
                float p2 = __builtin_amdgcn_exp2f(S[g][kt][2] - nm2);          \
                float p3 = __builtin_amdgcn_exp2f(S[g][kt][3] - nm2);          \
                rs += (p0 + p1) + (p2 + p3);                                   \
                pk16x2 lo = __builtin_amdgcn_cvt_pkrtz(p0, p1);                \
                pk16x2 hi = __builtin_amdgcn_cvt_pkrtz(p2, p3);                \
                half4 pk;                                                      \
                pk[0] = (_Float16)lo[0]; pk[1] = (_Float16)lo[1];              \
                pk[2] = (_Float16)hi[0]; pk[3] = (_Float16)hi[1];              \
                pfrag[g][kt] = pk;                                             \
            }                                                                  \
            l_i[g] += rs;   /* per-lane partial; cross-quad sum deferred */    \
        }                                                                      \
        _Pragma("unroll")                                                      \
        for (int c = 0; c < 2; ++c) {                                          \
            _Pragma("unroll")                                                  \
            for (int nt = 0; nt < 4; ++nt) {                                   \
                const _Float16* vr = (VB) + (l15 + 16 * nt) * 64               \
                    + (((quad * 2 + c) ^ ksw) * 8);                            \
                half8 vf = *(const half8*)vr;                                  \
                half4 va = __builtin_shufflevector(vf, vf, 0, 1, 2, 3);        \
                half4 vb = __builtin_shufflevector(vf, vf, 4, 5, 6, 7);        \
                acc[0][nt] = mfma_k16(va, pfrag[0][2 * c], acc[0][nt]);        \
                acc[1][nt] = mfma_k16(va, pfrag[1][2 * c], acc[1][nt]);        \
                acc[0][nt] = mfma_k16(vb, pfrag[0][2 * c + 1], acc[0][nt]);    \
                acc[1][nt] = mfma_k16(vb, pfrag[1][2 * c + 1], acc[1][nt]);    \
            }                                                                  \
        }                                                                      \
    } while (0)

    STAGE(0, Ksm0, Vsm0);
    for (int kt = 0; kt < NKT_SPLIT; kt += 2) {
        __syncthreads();
        if (kt + 1 < NKT_SPLIT) STAGE(kt + 1, Ksm1, Vsm1);
        COMPUTE(Ksm0, Vsm0);
        __syncthreads();
        if (kt + 2 < NKT_SPLIT) STAGE(kt + 2, Ksm0, Vsm0);
        COMPUTE(Ksm1, Vsm1);
    }

    // ---- partial epilogue: finish l (2 shfls), store normalized f16 O ----
    const int sb = (split << 4) | bh;
    #pragma unroll
    for (int g = 0; g < 2; ++g) {
        float lf = l_i[g];
        lf += __shfl_xor(lf, 16);
        lf += __shfl_xor(lf, 32);
        float inv_l = 1.0f / lf;
        int myq = q0 + g * 16 + l15;
        size_t pb = ((size_t)sb * HW + myq) * DH;
        #pragma unroll
        for (int nt = 0; nt < 4; ++nt) {
            pk16x2 lo = __builtin_amdgcn_cvt_pkrtz(acc[g][nt][0] * inv_l,
                                                   acc[g][nt][1] * inv_l);
            pk16x2 hi = __builtin_amdgcn_cvt_pkrtz(acc[g][nt][2] * inv_l,
                                                   acc[g][nt][3] * inv_l);
            half4 oh;
            oh[0] = (_Float16)lo[0]; oh[1] = (_Float16)lo[1];
            oh[2] = (_Float16)hi[0]; oh[3] = (_Float16)hi[1];
            *(half4*)(Pacc + pb + nt * 16 + quad * 4) = oh;
        }
        if (quad == 0) {
            float2 ml; ml.x = m_i[g]; ml.y = lf;
            *(float2*)(Pml + ((size_t)sb * HW + myq) * 2) = ml;
        }
    }
    #undef STAGE
    #undef COMPUTE
}

// ---------- combine: merge 4 splits + wp/bp epilogue ----------
__global__ __launch_bounds__(256) void combine_kernel(
    const _Float16* __restrict__ Pacc, const float* __restrict__ Pml,
    const float* __restrict__ wp, const float* __restrict__ bp,
    float* __restrict__ out)
{
    int t = blockIdx.x * 256 + threadIdx.x;   // 16 bh x 4096 q x 16 ch-quads
    int c4 = (t & 15) * 4;
    int q = (t >> 4) & 4095;
    int bh = t >> 16;
    float2 ml[NSPLIT];
    size_t r[NSPLIT];
    float m = -1e30f;
    #pragma unroll
    for (int s = 0; s < NSPLIT; ++s) {
        r[s] = (size_t)((s << 4) | bh) * HW + q;
        ml[s] = *(const float2*)(Pml + r[s] * 2);
        m = fmaxf(m, ml[s].x);
    }
    float w[NSPLIT], wsum = 0.f;
    #pragma unroll
    for (int s = 0; s < NSPLIT; ++s) {
        w[s] = ml[s].y * __builtin_amdgcn_exp2f(ml[s].x - m);
        wsum += w[s];
    }
    float inv = 1.0f / wsum;
    floatx4 oacc = {0.f, 0.f, 0.f, 0.f};
    #pragma unroll
    for (int s = 0; s < NSPLIT; ++s) {
        half4 a = *(const half4*)(Pacc + r[s] * DH + c4);
        float ws = w[s] * inv;
        #pragma unroll
        for (int j = 0; j < 4; ++j) oacc[j] += (float)a[j] * ws;
    }
    int h = bh & 3, b = bh >> 2;
    int chg = h * DH + c4;
    floatx4 wp4 = *(const floatx4*)(wp + chg);
    floatx4 bp4 = *(const floatx4*)(bp + chg);
    floatx4 o;
    #pragma unroll
    for (int j = 0; j < 4; ++j) o[j] = oacc[j] * wp4[j] + bp4[j];
    *(floatx4*)(out + ((size_t)b * HW + q) * CCH + chg) = o;
}

extern "C" void kernel_launch(void* const* d_in, const int* in_sizes, int n_in,
                              void* d_out, int out_size, void* d_ws, size_t ws_size,
                              hipStream_t stream) {
    const float* q_in = (const float*)d_in[0];
    const float* k_in = (const float*)d_in[1];
    const float* v_in = (const float*)d_in[2];
    const float* wq = (const float*)d_in[3];
    const float* bq = (const float*)d_in[4];
    const float* wk = (const float*)d_in[5];
    const float* bk = (const float*)d_in[6];
    const float* wv = (const float*)d_in[7];
    const float* bv = (const float*)d_in[8];
    const float* wp = (const float*)d_in[9];
    const float* bp = (const float*)d_in[10];
    float* out = (float*)d_out;

    const size_t tensor_halves = (size_t)4 * NH * HW * DH;   // 4 Mi halves = 8MB
    _Float16* Qhat = (_Float16*)d_ws;
    _Float16* Khat = Qhat + tensor_halves;
    _Float16* Vthat = Khat + tensor_halves;
    _Float16* Pacc = Vthat + tensor_halves;                  // 4 splits: 33.5MB
    float* Pml = (float*)(Pacc + NSPLIT * tensor_halves);    // 2MB

    prepass_all<<<dim3(4096 + 1024), 256, 0, stream>>>(
        q_in, k_in, v_in, wq, bq, wk, bk, wv, bv, Qhat, Khat, Vthat);
    attn_kernel<<<dim3(HW / QTILE, 4 * NH, NSPLIT), 512, 0, stream>>>(
        Qhat, Khat, Vthat, Pacc, Pml);
    combine_kernel<<<dim3(4096), 256, 0, stream>>>(Pacc, Pml, wp, bp, out);
}

// Round 8
// 211.292 us; speedup vs baseline: 3.8375x; 3.8375x over previous
//
#include <hip/hip_runtime.h>

// SpatialAttention B=4 HW=4096 C=256 NH=4 d=64 — f16 MFMA flash attention.
// R8 = R7 with the spill fixed: launch_bounds(512,4) (128-VGPR budget; R7's
// (512,8) forced 64 -> VGPR=32 + 1.4GB scratch spill). QTILE=256 halves
// fabric staging traffic vs R6; NSPLIT=2 -> grid 512 = exactly 2 blocks/CU
// (16 waves/CU); V stored in PV-fragment order w/ baked XOR swizzle.

#define HW 4096
#define CCH 256
#define DH 64
#define NH 4
#define QTILE 256
#define KTILE 64
#define NSPLIT 2
#define NKT_SPLIT (HW / NSPLIT / KTILE)   // 32
#define LOG2E 1.44269504088896340736f

typedef __attribute__((ext_vector_type(8))) _Float16 half8;
typedef __attribute__((ext_vector_type(4))) _Float16 half4;
typedef __attribute__((ext_vector_type(2))) __fp16 pk16x2;   // cvt_pkrtz native type
typedef __attribute__((ext_vector_type(4))) float floatx4;

typedef __attribute__((address_space(1))) const unsigned int gbl_u32;
typedef __attribute__((address_space(3))) unsigned int lds_u32;

__device__ __forceinline__ void gload_lds16(const void* g, void* l) {
    __builtin_amdgcn_global_load_lds((gbl_u32*)g, (lds_u32*)l, 16, 0, 0);
}
__device__ __forceinline__ floatx4 mfma_k32(half8 a, half8 b, floatx4 c) {
    return __builtin_amdgcn_mfma_f32_16x16x32_f16(a, b, c, 0, 0, 0);
}
__device__ __forceinline__ floatx4 mfma_k16(half4 a, half4 b, floatx4 c) {
    return __builtin_amdgcn_mfma_f32_16x16x16f16(a, b, c, 0, 0, 0);
}

// ---------- fused prepass ----------
// blocks [0,4096): Qhat/Khat elementwise (scale*log2e folded into Q)
// blocks [4096,5120): Vthat transpose into PV-fragment order + XOR swizzle
__global__ __launch_bounds__(256) void prepass_all(
    const float* __restrict__ q_in, const float* __restrict__ k_in,
    const float* __restrict__ v_in,
    const float* __restrict__ wq, const float* __restrict__ bq,
    const float* __restrict__ wk, const float* __restrict__ bk,
    const float* __restrict__ wv, const float* __restrict__ bv,
    _Float16* __restrict__ Qhat, _Float16* __restrict__ Khat,
    _Float16* __restrict__ Vthat)
{
    if (blockIdx.x < 4096) {
        int idx = (blockIdx.x * 256 + threadIdx.x) * 4;
        int b = idx >> 20;
        int rem = idx & ((1 << 20) - 1);
        int row = rem >> 8;
        int c = rem & 255;
        int h = c >> 6;
        int ch = c & 63;
        floatx4 q4 = *(const floatx4*)(q_in + idx);
        floatx4 k4 = *(const floatx4*)(k_in + idx);
        floatx4 wq4 = *(const floatx4*)(wq + c);
        floatx4 bq4 = *(const floatx4*)(bq + c);
        floatx4 wk4 = *(const floatx4*)(wk + c);
        floatx4 bk4 = *(const floatx4*)(bk + c);
        const float qsc = 0.125f * LOG2E;
        half4 qh, kh;
        qh[0] = (_Float16)((q4.x * wq4.x + bq4.x) * qsc);
        qh[1] = (_Float16)((q4.y * wq4.y + bq4.y) * qsc);
        qh[2] = (_Float16)((q4.z * wq4.z + bq4.z) * qsc);
        qh[3] = (_Float16)((q4.w * wq4.w + bq4.w) * qsc);
        kh[0] = (_Float16)(k4.x * wk4.x + bk4.x);
        kh[1] = (_Float16)(k4.y * wk4.y + bk4.y);
        kh[2] = (_Float16)(k4.z * wk4.z + bk4.z);
        kh[3] = (_Float16)(k4.w * wk4.w + bk4.w);
        size_t o = ((size_t)(b * NH + h) * HW + row) * DH + ch;
        *(half4*)(Qhat + o) = qh;
        *(half4*)(Khat + o) = kh;
    } else {
        __shared__ _Float16 Lt[64 * 68];
        int bx = blockIdx.x - 4096;
        int t = threadIdx.x;
        int key0 = (bx & 63) * 64;
        int bh = bx >> 6;
        int b = bh >> 2, h = bh & 3;
        int c4 = (t & 15) * 4;
        floatx4 wv4 = *(const floatx4*)(wv + h * DH + c4);
        floatx4 bv4 = *(const floatx4*)(bv + h * DH + c4);
        #pragma unroll
        for (int p = 0; p < 4; ++p) {
            int key = p * 16 + (t >> 4);
            const float* vp = v_in + ((size_t)b * HW + key0 + key) * CCH + h * DH + c4;
            floatx4 v4 = *(const floatx4*)vp;
            half4 vh;
            vh[0] = (_Float16)(v4.x * wv4.x + bv4.x);
            vh[1] = (_Float16)(v4.y * wv4.y + bv4.y);
            vh[2] = (_Float16)(v4.z * wv4.z + bv4.z);
            vh[3] = (_Float16)(v4.w * wv4.w + bv4.w);
            *(half4*)(&Lt[key * 68 + c4]) = vh;
        }
        __syncthreads();
        // Store 64-key tile in PV-fragment order + row XOR swizzle:
        // stored group gpos of row d holds data group g = gpos ^ (d&7);
        // within group, element j is key(g,j) = ((2g+(j>>2))&3)*16 + (g>>1)*4 + (j&3)
        #pragma unroll
        for (int p = 0; p < 2; ++p) {
            int d = p * 32 + (t >> 3);      // channel / d-row
            int gpos = t & 7;               // stored group position
            int g = gpos ^ (d & 7);         // data group (swizzle baked)
            half8 v8;
            #pragma unroll
            for (int j = 0; j < 8; ++j) {
                int key = (((g * 2 + (j >> 2)) & 3) << 4) + ((g >> 1) << 2) + (j & 3);
                v8[j] = Lt[key * 68 + d];
            }
            *(half8*)(Vthat + ((size_t)bh * DH + d) * HW + key0 + gpos * 8) = v8;
        }
    }
}

// ---------- attention (transposed, register-P, 2-way key-split) ----------
__launch_bounds__(512, 4)
__global__ void attn_kernel(
    const _Float16* __restrict__ Qhat, const _Float16* __restrict__ Khat,
    const _Float16* __restrict__ Vthat,
    _Float16* __restrict__ Pacc, float* __restrict__ Pml)
{
    // dbuf: Ksm0 | Ksm1 | Vsm0 | Vsm1 (8KB each) = 32KB -> 2 blocks/CU
    __shared__ alignas(16) char pool[32768];
    _Float16* Ksm0 = (_Float16*)(pool);
    _Float16* Ksm1 = (_Float16*)(pool + 8192);
    _Float16* Vsm0 = (_Float16*)(pool + 16384);
    _Float16* Vsm1 = (_Float16*)(pool + 24576);

    const int tid = threadIdx.x;
    const int wave = tid >> 6;     // 0..7
    const int lane = tid & 63;
    const int l15 = lane & 15;
    const int quad = lane >> 4;
    const int ksw = l15 & 7;

    const int qtile = blockIdx.x;
    const int bh = blockIdx.y;
    const int split = blockIdx.z;
    const int keybase = split * (HW / NSPLIT);

    // Q B-frags: B[k=ch][n=q], lane holds ch = quad*8+j (+32), q = l15 (+16g)
    const int q0 = qtile * QTILE + wave * 32;
    half8 qfrag[2][2];
    #pragma unroll
    for (int g = 0; g < 2; ++g) {
        const _Float16* qp = Qhat + ((size_t)bh * HW + q0 + g * 16 + l15) * DH + quad * 8;
        qfrag[g][0] = *(const half8*)(qp);
        qfrag[g][1] = *(const half8*)(qp + 32);
    }

    // staging lane addresses; 8 waves cover 64 rows (1 K + 1 V gload per wave)
    const int srow = wave * 8 + (lane >> 3);
    const int sw = (lane & 7) ^ (lane >> 3);   // K row-XOR swizzle (in global addr)
    const _Float16* kgp = Khat + ((size_t)bh * HW + keybase + srow) * DH + sw * 8;
    const _Float16* vgp = Vthat + ((size_t)bh * DH + srow) * HW + keybase + (lane & 7) * 8;

    floatx4 acc[2][4];
    float m_i[2], l_i[2];
    #pragma unroll
    for (int g = 0; g < 2; ++g) {
        m_i[g] = -1e30f; l_i[g] = 0.0f;
        #pragma unroll
        for (int nt = 0; nt < 4; ++nt) { floatx4 z = {0.f,0.f,0.f,0.f}; acc[g][nt] = z; }
    }

    #define STAGE(kt, KB, VB) do {                                             \
        gload_lds16(kgp + (size_t)(kt) * (KTILE * DH), (KB) + wave * 512);     \
        gload_lds16(vgp + (size_t)(kt) * KTILE, (VB) + wave * 512);            \
    } while (0)

    #define COMPUTE(KB, VB) do {                                               \
        floatx4 S[2][4];                                                       \
        _Pragma("unroll")                                                      \
        for (int kt = 0; kt < 4; ++kt) {                                       \
            const _Float16* kr = (KB) + (l15 + 16 * kt) * 64;                  \
            half8 kf0 = *(const half8*)(kr + ((quad ^ ksw) * 8));              \
            half8 kf1 = *(const half8*)(kr + (((4 + quad) ^ ksw) * 8));        \
            _Pragma("unroll")                                                  \
            for (int g = 0; g < 2; ++g) {                                      \
                floatx4 s = {0.f, 0.f, 0.f, 0.f};                              \
                s = mfma_k32(kf0, qfrag[g][0], s);                             \
                s = mfma_k32(kf1, qfrag[g][1], s);                             \
                S[g][kt] = s;                                                  \
            }                                                                  \
        }                                                                      \
        half4 pfrag[2][4];                                                     \
        _Pragma("unroll")                                                      \
        for (int g = 0; g < 2; ++g) {                                          \
            float mx = fmaxf(fmaxf(fmaxf(S[g][0][0], S[g][0][1]),              \
                                   fmaxf(S[g][0][2], S[g][0][3])),             \
                             fmaxf(fmaxf(S[g][1][0], S[g][1][1]),              \
                                   fmaxf(S[g][1][2], S[g][1][3])));            \
            float mx2 = fmaxf(fmaxf(fmaxf(S[g][2][0], S[g][2][1]),             \
                                    fmaxf(S[g][2][2], S[g][2][3])),            \
                              fmaxf(fmaxf(S[g][3][0], S[g][3][1]),             \
                                    fmaxf(S[g][3][2], S[g][3][3])));           \
            mx = fmaxf(mx, mx2);                                               \
            mx = fmaxf(mx, __shfl_xor(mx, 16));                                \
            mx = fmaxf(mx, __shfl_xor(mx, 32));                                \
            if (__any(mx > m_i[g])) {                                          \
                float nm = fmaxf(m_i[g], mx);                                  \
                float alpha = __builtin_amdgcn_exp2f(m_i[g] - nm);             \
                l_i[g] *= alpha;                                               \
                _Pragma("unroll")                                              \
                for (int nt = 0; nt < 4; ++nt) acc[g][nt] *= alpha;            \
                m_i[g] = nm;                                                   \
            }                                                                  \
            float nm2 = m_i[g];                                                \
            float rs = 0.0f;                                                   \
            _Pragma("unroll")                                                  \
            for (int kt = 0; kt < 4; ++kt) {                                   \
                float p0 = __builtin_amdgcn_exp2f(S[g][kt][0] - nm2);          \
                float p1 = __builtin_amdgcn_exp2f(S[g][kt][1] - nm2);          \
                float p2 = __builtin_amdgcn_exp2f(S[g][kt][2] - nm2);          \
                float p3 = __builtin_amdgcn_exp2f(S[g][kt][3] - nm2);          \
                rs += (p0 + p1) + (p2 + p3);                                   \
                pk16x2 lo = __builtin_amdgcn_cvt_pkrtz(p0, p1);                \
                pk16x2 hi = __builtin_amdgcn_cvt_pkrtz(p2, p3);                \
                half4 pk;                                                      \
                pk[0] = (_Float16)lo[0]; pk[1] = (_Float16)lo[1];              \
                pk[2] = (_Float16)hi[0]; pk[3] = (_Float16)hi[1];              \
                pfrag[g][kt] = pk;                                             \
            }                                                                  \
            l_i[g] += rs;   /* per-lane partial; cross-quad sum deferred */    \
        }                                                                      \
        _Pragma("unroll")                                                      \
        for (int c = 0; c < 2; ++c) {                                          \
            _Pragma("unroll")                                                  \
            for (int nt = 0; nt < 4; ++nt) {                                   \
                const _Float16* vr = (VB) + (l15 + 16 * nt) * 64               \
                    + (((quad * 2 + c) ^ ksw) * 8);                            \
                half8 vf = *(const half8*)vr;                                  \
                half4 va = __builtin_shufflevector(vf, vf, 0, 1, 2, 3);        \
                half4 vb = __builtin_shufflevector(vf, vf, 4, 5, 6, 7);        \
                acc[0][nt] = mfma_k16(va, pfrag[0][2 * c], acc[0][nt]);        \
                acc[1][nt] = mfma_k16(va, pfrag[1][2 * c], acc[1][nt]);        \
                acc[0][nt] = mfma_k16(vb, pfrag[0][2 * c + 1], acc[0][nt]);    \
                acc[1][nt] = mfma_k16(vb, pfrag[1][2 * c + 1], acc[1][nt]);    \
            }                                                                  \
        }                                                                      \
    } while (0)

    STAGE(0, Ksm0, Vsm0);
    for (int kt = 0; kt < NKT_SPLIT; kt += 2) {
        __syncthreads();
        if (kt + 1 < NKT_SPLIT) STAGE(kt + 1, Ksm1, Vsm1);
        COMPUTE(Ksm0, Vsm0);
        __syncthreads();
        if (kt + 2 < NKT_SPLIT) STAGE(kt + 2, Ksm0, Vsm0);
        COMPUTE(Ksm1, Vsm1);
    }

    // ---- partial epilogue: finish l (2 shfls), store normalized f16 O ----
    const int sb = (split << 4) | bh;
    #pragma unroll
    for (int g = 0; g < 2; ++g) {
        float lf = l_i[g];
        lf += __shfl_xor(lf, 16);
        lf += __shfl_xor(lf, 32);
        float inv_l = 1.0f / lf;
        int myq = q0 + g * 16 + l15;
        size_t pb = ((size_t)sb * HW + myq) * DH;
        #pragma unroll
        for (int nt = 0; nt < 4; ++nt) {
            pk16x2 lo = __builtin_amdgcn_cvt_pkrtz(acc[g][nt][0] * inv_l,
                                                   acc[g][nt][1] * inv_l);
            pk16x2 hi = __builtin_amdgcn_cvt_pkrtz(acc[g][nt][2] * inv_l,
                                                   acc[g][nt][3] * inv_l);
            half4 oh;
            oh[0] = (_Float16)lo[0]; oh[1] = (_Float16)lo[1];
            oh[2] = (_Float16)hi[0]; oh[3] = (_Float16)hi[1];
            *(half4*)(Pacc + pb + nt * 16 + quad * 4) = oh;
        }
        if (quad == 0) {
            float2 ml; ml.x = m_i[g]; ml.y = lf;
            *(float2*)(Pml + ((size_t)sb * HW + myq) * 2) = ml;
        }
    }
    #undef STAGE
    #undef COMPUTE
}

// ---------- combine: merge 2 splits + wp/bp epilogue ----------
__global__ __launch_bounds__(256) void combine_kernel(
    const _Float16* __restrict__ Pacc, const float* __restrict__ Pml,
    const float* __restrict__ wp, const float* __restrict__ bp,
    float* __restrict__ out)
{
    int t = blockIdx.x * 256 + threadIdx.x;   // 16 bh x 4096 q x 16 ch-quads
    int c4 = (t & 15) * 4;
    int q = (t >> 4) & 4095;
    int bh = t >> 16;
    float2 ml[NSPLIT];
    size_t r[NSPLIT];
    float m = -1e30f;
    #pragma unroll
    for (int s = 0; s < NSPLIT; ++s) {
        r[s] = (size_t)((s << 4) | bh) * HW + q;
        ml[s] = *(const float2*)(Pml + r[s] * 2);
        m = fmaxf(m, ml[s].x);
    }
    float w[NSPLIT], wsum = 0.f;
    #pragma unroll
    for (int s = 0; s < NSPLIT; ++s) {
        w[s] = ml[s].y * __builtin_amdgcn_exp2f(ml[s].x - m);
        wsum += w[s];
    }
    float inv = 1.0f / wsum;
    floatx4 oacc = {0.f, 0.f, 0.f, 0.f};
    #pragma unroll
    for (int s = 0; s < NSPLIT; ++s) {
        half4 a = *(const half4*)(Pacc + r[s] * DH + c4);
        float ws = w[s] * inv;
        #pragma unroll
        for (int j = 0; j < 4; ++j) oacc[j] += (float)a[j] * ws;
    }
    int h = bh & 3, b = bh >> 2;
    int chg = h * DH + c4;
    floatx4 wp4 = *(const floatx4*)(wp + chg);
    floatx4 bp4 = *(const floatx4*)(bp + chg);
    floatx4 o;
    #pragma unroll
    for (int j = 0; j < 4; ++j) o[j] = oacc[j] * wp4[j] + bp4[j];
    *(floatx4*)(out + ((size_t)b * HW + q) * CCH + chg) = o;
}

extern "C" void kernel_launch(void* const* d_in, const int* in_sizes, int n_in,
                              void* d_out, int out_size, void* d_ws, size_t ws_size,
                              hipStream_t stream) {
    const float* q_in = (const float*)d_in[0];
    const float* k_in = (const float*)d_in[1];
    const float* v_in = (const float*)d_in[2];
    const float* wq = (const float*)d_in[3];
    const float* bq = (const float*)d_in[4];
    const float* wk = (const float*)d_in[5];
    const float* bk = (const float*)d_in[6];
    const float* wv = (const float*)d_in[7];
    const float* bv = (const float*)d_in[8];
    const float* wp = (const float*)d_in[9];
    const float* bp = (const float*)d_in[10];
    float* out = (float*)d_out;

    const size_t tensor_halves = (size_t)4 * NH * HW * DH;   // 4 Mi halves = 8MB
    _Float16* Qhat = (_Float16*)d_ws;
    _Float16* Khat = Qhat + tensor_halves;
    _Float16* Vthat = Khat + tensor_halves;
    _Float16* Pacc = Vthat + tensor_halves;                  // 2 splits: 16.8MB
    float* Pml = (float*)(Pacc + NSPLIT * tensor_halves);    // 1MB

    prepass_all<<<dim3(4096 + 1024), 256, 0, stream>>>(
        q_in, k_in, v_in, wq, bq, wk, bk, wv, bv, Qhat, Khat, Vthat);
    attn_kernel<<<dim3(HW / QTILE, 4 * NH, NSPLIT), 512, 0, stream>>>(
        Qhat, Khat, Vthat, Pacc, Pml);
    combine_kernel<<<dim3(4096), 256, 0, stream>>>(Pacc, Pml, wp, bp, out);
}